// Round 1
// baseline (159.879 us; speedup 1.0000x reference)
//
#include <hip/hip_runtime.h>
#include <stdint.h>

#define B_SZ 1024
#define M_SZ 209
#define D_SZ 12288
#define S_SZ 2

#define BT   64              // B rows per block
#define MT   224             // padded M (14 * 16)
#define NCT  14              // 16-wide col tiles
#define KC   16              // split-K chunks
#define KCH  (D_SZ / KC)     // 768
#define BK   64              // K per staging iteration
#define NIT  (KCH / BK)      // 12
#define LDX  72              // LDS row stride in bf16 elems (64 + 8 pad)

typedef __attribute__((ext_vector_type(8))) short short8;
typedef __attribute__((ext_vector_type(4))) float floatx4;

__device__ __forceinline__ unsigned short f2bf(float f) {
    union { float f; uint32_t u; } v; v.f = f;
    uint32_t u = v.u;
    u += 0x7fffu + ((u >> 16) & 1u);   // round-to-nearest-even
    return (unsigned short)(u >> 16);
}

// Fused distance-GEMM: accumulates dot(x_i, c_j) partials (split-K) and ||x||^2
__global__ __launch_bounds__(256, 2) void rbf_main(
    const float* __restrict__ x, const float* __restrict__ c,
    float* __restrict__ dotp, float* __restrict__ xx)
{
    __shared__ unsigned short sx[BT * LDX];
    __shared__ unsigned short sc[MT * LDX];
    __shared__ float redbuf[256];

    const int t      = threadIdx.x;
    const int kchunk = blockIdx.x;
    const int bchunk = blockIdx.y;
    const int wave   = t >> 6;
    const int lane   = t & 63;
    const int quad   = lane >> 4;
    const int mrow   = lane & 15;

    floatx4 acc[NCT];
    const floatx4 zero4 = {0.f, 0.f, 0.f, 0.f};
#pragma unroll
    for (int i = 0; i < NCT; ++i) acc[i] = zero4;

    const int r  = t >> 2;        // staging row within tile, 0..63
    const int cb = (t & 3) * 4;   // staging float4 col base

    const float* xp = x + (size_t)(bchunk * BT + r) * D_SZ + kchunk * KCH + cb;
    const float* cp = c + (size_t)r * D_SZ + kchunk * KCH + cb;

    float sxx = 0.f;

    for (int it = 0; it < NIT; ++it) {
        // ---- stage x tile (64 x 64), fp32 -> bf16, accumulate ||x||^2 partial
#pragma unroll
        for (int f = 0; f < 4; ++f) {
            float4 v = *(const float4*)(xp + f * 16);
            sxx += v.x * v.x + v.y * v.y + v.z * v.z + v.w * v.w;
            unsigned short* d = &sx[r * LDX + f * 16 + cb];
            d[0] = f2bf(v.x); d[1] = f2bf(v.y); d[2] = f2bf(v.z); d[3] = f2bf(v.w);
        }
        // ---- stage c tile (224 x 64) in 4 row-blocks (rows >= 209 zeroed)
#pragma unroll
        for (int rb = 0; rb < 4; ++rb) {
            if (rb < 3 || r < 32) {
                int  crow  = rb * 64 + r;
                bool valid = crow < M_SZ;
#pragma unroll
                for (int f = 0; f < 4; ++f) {
                    float4 v = valid ? *(const float4*)(cp + (size_t)rb * 64 * D_SZ + f * 16)
                                     : make_float4(0.f, 0.f, 0.f, 0.f);
                    unsigned short* d = &sc[crow * LDX + f * 16 + cb];
                    d[0] = f2bf(v.x); d[1] = f2bf(v.y); d[2] = f2bf(v.z); d[3] = f2bf(v.w);
                }
            }
        }
        __syncthreads();

        // ---- MFMA: 2 k-steps of 32 over this BK=64 slab
        const unsigned short* ax = &sx[(wave * 16 + mrow) * LDX + quad * 8];
        const unsigned short* bx = &sc[mrow * LDX + quad * 8];
#pragma unroll
        for (int k0 = 0; k0 < BK; k0 += 32) {
            short8 a = *(const short8*)(ax + k0);
#pragma unroll
            for (int ct = 0; ct < NCT; ++ct) {
                short8 b = *(const short8*)(bx + ct * 16 * LDX + k0);
                acc[ct] = __builtin_amdgcn_mfma_f32_16x16x32_bf16(a, b, acc[ct], 0, 0, 0);
            }
        }
        __syncthreads();
        xp += BK;
        cp += BK;
    }

    // ---- epilogue: merge dot partials (C/D layout: col=lane&15, row=quad*4+reg)
    const int gi0 = bchunk * BT + wave * 16 + quad * 4;
#pragma unroll
    for (int ct = 0; ct < NCT; ++ct) {
        int gj = ct * 16 + mrow;
        if (gj < M_SZ) {
#pragma unroll
            for (int rg = 0; rg < 4; ++rg) {
                atomicAdd(&dotp[(size_t)(gi0 + rg) * M_SZ + gj], acc[ct][rg]);
            }
        }
    }

    // ---- ||x||^2 partials: 4 threads per row -> 1 atomic per row
    redbuf[t] = sxx;
    __syncthreads();
    if ((t & 3) == 0) {
        float s = redbuf[t] + redbuf[t + 1] + redbuf[t + 2] + redbuf[t + 3];
        atomicAdd(&xx[bchunk * BT + r], s);
    }
}

// ||c_j||^2, one block per center
__global__ __launch_bounds__(256) void rbf_cc(const float* __restrict__ c,
                                              float* __restrict__ cc)
{
    __shared__ float wsum[4];
    const int j = blockIdx.x;
    const float4* c4 = (const float4*)(c + (size_t)j * D_SZ);
    float s = 0.f;
    for (int i = threadIdx.x; i < D_SZ / 4; i += 256) {
        float4 v = c4[i];
        s += v.x * v.x + v.y * v.y + v.z * v.z + v.w * v.w;
    }
#pragma unroll
    for (int off = 32; off > 0; off >>= 1) s += __shfl_down(s, off);
    if ((threadIdx.x & 63) == 0) wsum[threadIdx.x >> 6] = s;
    __syncthreads();
    if (threadIdx.x == 0) cc[j] = wsum[0] + wsum[1] + wsum[2] + wsum[3];
}

// finalize: d2 = xx + cc - 2*dot; radial = exp(-sqrt(d2)/sigma^2); out = radial @ W^T + b
__global__ __launch_bounds__(256) void rbf_fin(
    const float* __restrict__ dotp, const float* __restrict__ xx,
    const float* __restrict__ cc, const float* __restrict__ sigma,
    const float* __restrict__ W, const float* __restrict__ bias,
    float* __restrict__ out)
{
    const int wave = threadIdx.x >> 6, lane = threadIdx.x & 63;
    const int i = blockIdx.x * 4 + wave;      // one wave per output row
    const float xxi = xx[i];
    float a0 = 0.f, a1 = 0.f;
    for (int j = lane; j < M_SZ; j += 64) {
        float d2 = xxi + cc[j] - 2.f * dotp[(size_t)i * M_SZ + j];
        d2 = fmaxf(d2, 0.f);
        float dist = sqrtf(d2);
        float sg = sigma[j];
        float rad = __expf(-dist / (sg * sg));
        a0 += rad * W[j];
        a1 += rad * W[M_SZ + j];
    }
#pragma unroll
    for (int off = 32; off > 0; off >>= 1) {
        a0 += __shfl_down(a0, off);
        a1 += __shfl_down(a1, off);
    }
    if (lane == 0) {
        out[i * 2 + 0] = a0 + bias[0];
        out[i * 2 + 1] = a1 + bias[1];
    }
}

extern "C" void kernel_launch(void* const* d_in, const int* in_sizes, int n_in,
                              void* d_out, int out_size, void* d_ws, size_t ws_size,
                              hipStream_t stream)
{
    const float* x     = (const float*)d_in[0];
    const float* c     = (const float*)d_in[1];
    const float* sigma = (const float*)d_in[2];
    const float* W     = (const float*)d_in[3];
    const float* bias  = (const float*)d_in[4];
    float* out = (float*)d_out;

    float* dotp = (float*)d_ws;                       // [B, M] fp32
    float* xx   = dotp + (size_t)B_SZ * M_SZ;         // [B]
    float* cc   = xx + B_SZ;                          // [M]

    // zero the atomic accumulation targets (ws is re-poisoned before every call)
    hipMemsetAsync(d_ws, 0, ((size_t)B_SZ * M_SZ + B_SZ) * sizeof(float), stream);

    rbf_cc<<<M_SZ, 256, 0, stream>>>(c, cc);
    rbf_main<<<dim3(KC, B_SZ / BT), 256, 0, stream>>>(x, c, dotp, xx);
    rbf_fin<<<B_SZ / 4, 256, 0, stream>>>(dotp, xx, cc, sigma, W, bias, out);
}

// Round 2
// 125.182 us; speedup vs baseline: 1.2772x; 1.2772x over previous
//
#include <hip/hip_runtime.h>
#include <hip/hip_bf16.h>
#include <stdint.h>

#define B_SZ 1024
#define M_SZ 209
#define D_SZ 12288
#define S_SZ 2

#define BT   64              // B rows per block
#define MT   224             // padded M (14 * 16)
#define NCT  14              // 16-wide col tiles
#define KC   48              // split-K chunks -> grid 768 = 3 blocks/CU
#define KCH  (D_SZ / KC)     // 256
#define BK   64              // K per staging iteration
#define NIT  (KCH / BK)      // 4
#define LDX  72              // LDS row stride in bf16 elems (64 + 8 pad)

// ws layout (floats): [xx: B][cc: M][pad -> 1280][dot: KC*B*M (slab) or B*M (atomic)]
#define WS_DOT_OFF 1280

typedef __attribute__((ext_vector_type(8))) short short8;
typedef __attribute__((ext_vector_type(4))) float floatx4;

__device__ __forceinline__ uint32_t pk2(float lo, float hi) {
    union { __hip_bfloat162 h; uint32_t u; } cv;
    cv.h = __float22bfloat162_rn(float2{lo, hi});
    return cv.u;
}

// Fused distance-GEMM: dot(x_i,c_j) split-K partials + ||x||^2 + ||c||^2
__global__ __launch_bounds__(256, 3) void rbf_main(
    const float* __restrict__ x, const float* __restrict__ c,
    float* __restrict__ dot, float* __restrict__ xx, float* __restrict__ cc,
    int atomic_mode)
{
    __shared__ unsigned short sx[BT * LDX];
    __shared__ unsigned short sc[MT * LDX];

    const int t      = threadIdx.x;
    const int kchunk = blockIdx.x;
    const int bchunk = blockIdx.y;
    const int wave   = t >> 6;
    const int lane   = t & 63;
    const int quad   = lane >> 4;
    const int mrow   = lane & 15;

    floatx4 acc[NCT];
    const floatx4 zero4 = {0.f, 0.f, 0.f, 0.f};
#pragma unroll
    for (int i = 0; i < NCT; ++i) acc[i] = zero4;

    const int r     = t >> 2;        // staging row within 64-row band
    const int cbase = (t & 3) * 16;  // 16 contiguous floats per thread

    const float* xp = x + (size_t)(bchunk * BT + r) * D_SZ + kchunk * KCH + cbase;
    const float* cp = c + (size_t)r * D_SZ + kchunk * KCH + cbase;
    const bool do_cc = (bchunk == 0);

    float sxx = 0.f;
    float scc[4] = {0.f, 0.f, 0.f, 0.f};

    for (int it = 0; it < NIT; ++it) {
        // ---- x tile (64x64): 16 floats/thread, cvt_pk -> 2x ds_write_b128
        {
            float4 v0 = *(const float4*)(xp + 0);
            float4 v1 = *(const float4*)(xp + 4);
            float4 v2 = *(const float4*)(xp + 8);
            float4 v3 = *(const float4*)(xp + 12);
            sxx += v0.x*v0.x + v0.y*v0.y + v0.z*v0.z + v0.w*v0.w
                 + v1.x*v1.x + v1.y*v1.y + v1.z*v1.z + v1.w*v1.w
                 + v2.x*v2.x + v2.y*v2.y + v2.z*v2.z + v2.w*v2.w
                 + v3.x*v3.x + v3.y*v3.y + v3.z*v3.z + v3.w*v3.w;
            uint4 w0 = { pk2(v0.x,v0.y), pk2(v0.z,v0.w), pk2(v1.x,v1.y), pk2(v1.z,v1.w) };
            uint4 w1 = { pk2(v2.x,v2.y), pk2(v2.z,v2.w), pk2(v3.x,v3.y), pk2(v3.z,v3.w) };
            *(uint4*)(&sx[r * LDX + cbase])     = w0;
            *(uint4*)(&sx[r * LDX + cbase + 8]) = w1;
        }
        // ---- c tile (224x64) in 4 row-blocks (rows >= 209 zeroed)
#pragma unroll
        for (int rb = 0; rb < 4; ++rb) {
            const int crow = rb * 64 + r;
            if (rb < 3 || r < 32) {
                const bool valid = crow < M_SZ;
                const float* p = cp + (size_t)rb * 64 * D_SZ;
                float4 v0, v1, v2, v3;
                if (valid) {
                    v0 = *(const float4*)(p + 0);  v1 = *(const float4*)(p + 4);
                    v2 = *(const float4*)(p + 8);  v3 = *(const float4*)(p + 12);
                } else {
                    v0 = v1 = v2 = v3 = make_float4(0.f, 0.f, 0.f, 0.f);
                }
                if (do_cc && valid) {
                    scc[rb] += v0.x*v0.x + v0.y*v0.y + v0.z*v0.z + v0.w*v0.w
                             + v1.x*v1.x + v1.y*v1.y + v1.z*v1.z + v1.w*v1.w
                             + v2.x*v2.x + v2.y*v2.y + v2.z*v2.z + v2.w*v2.w
                             + v3.x*v3.x + v3.y*v3.y + v3.z*v3.z + v3.w*v3.w;
                }
                uint4 w0 = { pk2(v0.x,v0.y), pk2(v0.z,v0.w), pk2(v1.x,v1.y), pk2(v1.z,v1.w) };
                uint4 w1 = { pk2(v2.x,v2.y), pk2(v2.z,v2.w), pk2(v3.x,v3.y), pk2(v3.z,v3.w) };
                *(uint4*)(&sc[crow * LDX + cbase])     = w0;
                *(uint4*)(&sc[crow * LDX + cbase + 8]) = w1;
            }
        }
        __syncthreads();

        // ---- MFMA: 2 k-steps of 32 over this BK=64 slab
        const unsigned short* ax = &sx[(wave * 16 + mrow) * LDX + quad * 8];
        const unsigned short* bx = &sc[mrow * LDX + quad * 8];
#pragma unroll
        for (int k0 = 0; k0 < BK; k0 += 32) {
            short8 a = *(const short8*)(ax + k0);
#pragma unroll
            for (int ct = 0; ct < NCT; ++ct) {
                short8 b = *(const short8*)(bx + ct * 16 * LDX + k0);
                acc[ct] = __builtin_amdgcn_mfma_f32_16x16x32_bf16(a, b, acc[ct], 0, 0, 0);
            }
        }
        __syncthreads();
        xp += BK;
        cp += BK;
    }

    // ---- dot partials (C/D layout: col=lane&15, row=quad*4+reg)
    float* dst = atomic_mode ? dot : dot + (size_t)kchunk * B_SZ * M_SZ;
    const int gi0 = bchunk * BT + wave * 16 + quad * 4;
#pragma unroll
    for (int ct = 0; ct < NCT; ++ct) {
        const int gj = ct * 16 + mrow;
        if (gj < M_SZ) {
#pragma unroll
            for (int rg = 0; rg < 4; ++rg) {
                const size_t idx = (size_t)(gi0 + rg) * M_SZ + gj;
                if (atomic_mode) atomicAdd(&dst[idx], acc[ct][rg]);
                else             dst[idx] = acc[ct][rg];
            }
        }
    }

    // ---- ||x||^2: reduce 4 staging lanes per row -> 1 atomic
    sxx += __shfl_down(sxx, 2);
    sxx += __shfl_down(sxx, 1);
    if ((t & 3) == 0) atomicAdd(&xx[bchunk * BT + r], sxx);

    // ---- ||c||^2 (bchunk==0 blocks only)
    if (do_cc) {
#pragma unroll
        for (int rb = 0; rb < 4; ++rb) {
            float s = scc[rb];
            s += __shfl_down(s, 2);
            s += __shfl_down(s, 1);
            const int crow = rb * 64 + r;
            if ((t & 3) == 0 && crow < M_SZ) atomicAdd(&cc[crow], s);
        }
    }
}

// finalize: reduce split-K, d2 = xx + cc - 2*dot, radial = exp(-sqrt/sig^2), @ W^T + b
template <int NKC>
__global__ __launch_bounds__(256) void rbf_fin(
    const float* __restrict__ dot, const float* __restrict__ xx,
    const float* __restrict__ cc, const float* __restrict__ sigma,
    const float* __restrict__ W, const float* __restrict__ bias,
    float* __restrict__ out)
{
    const int wave = threadIdx.x >> 6, lane = threadIdx.x & 63;
    const int i = blockIdx.x * 4 + wave;      // one wave per output row
    const float xxi = xx[i];
    float a0 = 0.f, a1 = 0.f;
    for (int j = lane; j < M_SZ; j += 64) {
        float s = 0.f;
#pragma unroll
        for (int k = 0; k < NKC; ++k)
            s += dot[(size_t)k * B_SZ * M_SZ + (size_t)i * M_SZ + j];
        float d2 = fmaxf(xxi + cc[j] - 2.f * s, 0.f);
        float sg = sigma[j];
        float rad = __expf(-sqrtf(d2) / (sg * sg));
        a0 += rad * W[j];
        a1 += rad * W[M_SZ + j];
    }
#pragma unroll
    for (int off = 32; off > 0; off >>= 1) {
        a0 += __shfl_down(a0, off);
        a1 += __shfl_down(a1, off);
    }
    if (lane == 0) {
        out[i * 2 + 0] = a0 + bias[0];
        out[i * 2 + 1] = a1 + bias[1];
    }
}

extern "C" void kernel_launch(void* const* d_in, const int* in_sizes, int n_in,
                              void* d_out, int out_size, void* d_ws, size_t ws_size,
                              hipStream_t stream)
{
    const float* x     = (const float*)d_in[0];
    const float* c     = (const float*)d_in[1];
    const float* sigma = (const float*)d_in[2];
    const float* W     = (const float*)d_in[3];
    const float* bias  = (const float*)d_in[4];
    float* out = (float*)d_out;

    float* xx  = (float*)d_ws;                 // [B]
    float* cc  = xx + B_SZ;                    // [M]
    float* dot = (float*)d_ws + WS_DOT_OFF;    // slab: [KC,B,M]; atomic: [B,M]

    const size_t slab_bytes = ((size_t)WS_DOT_OFF + (size_t)KC * B_SZ * M_SZ) * 4;
    const int atomic_mode = (ws_size < slab_bytes) ? 1 : 0;

    // zero atomic accumulation targets (xx, cc always; dot too in atomic mode)
    const size_t zero_bytes = atomic_mode
        ? ((size_t)WS_DOT_OFF + (size_t)B_SZ * M_SZ) * 4
        : (size_t)WS_DOT_OFF * 4;
    hipMemsetAsync(d_ws, 0, zero_bytes, stream);

    rbf_main<<<dim3(KC, B_SZ / BT), 256, 0, stream>>>(x, c, dot, xx, cc, atomic_mode);
    if (atomic_mode)
        rbf_fin<1><<<B_SZ / 4, 256, 0, stream>>>(dot, xx, cc, sigma, W, bias, out);
    else
        rbf_fin<KC><<<B_SZ / 4, 256, 0, stream>>>(dot, xx, cc, sigma, W, bias, out);
}